// Round 9
// baseline (115.659 us; speedup 1.0000x reference)
//
#include <hip/hip_runtime.h>

#define NAGENT 8192
#define NCELL 36
#define HIDDEN 128
#define CSTRIDE 37    // k2 LDS occ row stride (gcd(37,32)=1)
#define PWORDS 18     // 36 cells packed as 18 u32 (2 x u16)
#define NROWS 64      // 8x8 clamp grid: border rows absorb out-of-range points
#define NCHUNK 16
#define JCHUNK (NAGENT / NCHUNK)  // 512 js per block, 128 per wave
#define MARGIN 1.501f // interaction reach 1.5 + fp slack (conservative-safe)

typedef float v2f __attribute__((ext_vector_type(2)));

// workspace layout (u32 words)
#define WS_PARTIAL 0
#define WS_BCNT (NCHUNK * PWORDS * NAGENT)        // 256 bucket counts
#define WS_BCUR (WS_BCNT + 256)                   // 256 scatter cursors
#define WS_SIDX (WS_BCUR + 256)                   // 8192 sorted->orig index
#define WS_SOBS (WS_SIDX + NAGENT)                // 8192 float2 sorted positions

__device__ __forceinline__ int bucket_of(float2 o) {
  int bx = (int)__builtin_floorf((o.x + 4.0f) * 2.0f);
  int by = (int)__builtin_floorf((o.y + 4.0f) * 2.0f);
  bx = min(max(bx, 0), 15); by = min(max(by, 0), 15);
  return bx * 16 + by;
}

// S1: bucket counts (16x16 grid over [-4,4]^2, cell 0.5)
__global__ __launch_bounds__(256) void sort_count(
    const float2* __restrict__ obs, unsigned* __restrict__ bcnt) {
  const int a = blockIdx.x * 256 + threadIdx.x;
  atomicAdd(&bcnt[bucket_of(obs[a])], 1u);
}

// S2: exclusive scan of 256 bucket counts -> scatter cursors
__global__ __launch_bounds__(256) void sort_scan(
    const unsigned* __restrict__ bcnt, unsigned* __restrict__ bcur) {
  __shared__ unsigned sh[256];
  const int tid = threadIdx.x;
  const unsigned x = bcnt[tid];
  sh[tid] = x; __syncthreads();
  for (int off = 1; off < 256; off <<= 1) {
    unsigned v = (tid >= off) ? sh[tid - off] : 0u;
    __syncthreads(); sh[tid] += v; __syncthreads();
  }
  bcur[tid] = sh[tid] - x;  // exclusive
}

// S3: scatter agents into bucket-sorted order
__global__ __launch_bounds__(256) void sort_scatter(
    const float2* __restrict__ obs, unsigned* __restrict__ bcur,
    unsigned* __restrict__ sidx, float2* __restrict__ sobs) {
  const int a = blockIdx.x * 256 + threadIdx.x;
  const float2 o = obs[a];
  const unsigned pos = atomicAdd(&bcur[bucket_of(o)], 1u);
  sidx[pos] = (unsigned)a;
  sobs[pos] = o;
}

// ---------------------------------------------------------------------------
// k1: pairwise occupancy histogram over SORTED agents. Grid (NCHUNK, 128) =
// 2048 blocks, 8/CU, 32 waves/CU. lane = sorted agent; 4 waves x 128 js.
// k1 is LDS-ATOMIC-ISSUE-bound (~18 cyc per ds_add regardless of lanes/banks;
// R3/R7/R8 all ~30.5us at 4096 issues/CU). Sorting makes agent groups and
// j-batches spatially tight, so a 16-j batch whose bbox is > MARGIN from the
// group bbox (wave-uniform scalar test via ballot mask) is skipped WHOLESALE
// -- loads, VALU and atomics. Conservative test: a wrong bbox only loses the
// skip, never correctness. Expected skip ~35%.
// Per-point body identical to R8 (pk_fma + fmed3f clamp + cvt + ds_add into
// the 8x8 clamp grid; border rows discarded at harvest; self-pair lands at
// center row (4,4) and is subtracted in k2).
// ---------------------------------------------------------------------------
__global__ __launch_bounds__(256) void occ_hist_kernel(
    const float2* __restrict__ sobs, unsigned* __restrict__ partial) {
  __shared__ unsigned cnt[NROWS * 64];  // 16 KB -> 8 blocks/CU
  const int tid  = threadIdx.x;
  const int lane = tid & 63;
  const int wv   = tid >> 6;

#pragma unroll
  for (int k = tid; k < NROWS * 64; k += 256) cnt[k] = 0u;
  __syncthreads();

  const int agent = blockIdx.y * 64 + lane;
  const float2 oi = sobs[agent];
  const v2f two = {2.0f, 2.0f};
  const v2f cxy = {fmaf(oi.x, -2.0f, 3.0f), fmaf(oi.y, -2.0f, 3.0f)};
  unsigned* base = cnt + 9 * 64 + lane;

  // group bbox (same 64 agents in all 4 waves): wave min/max reduce
  float gxmin = oi.x, gxmax = oi.x, gymin = oi.y, gymax = oi.y;
#pragma unroll
  for (int m = 1; m < 64; m <<= 1) {
    gxmin = fminf(gxmin, __shfl_xor(gxmin, m));
    gxmax = fmaxf(gxmax, __shfl_xor(gxmax, m));
    gymin = fminf(gymin, __shfl_xor(gymin, m));
    gymax = fmaxf(gymax, __shfl_xor(gymax, m));
  }

  // j-batch bboxes: this wave's 128 js = 64 float4 (one per lane = js 2l,2l+1);
  // batch k (16 js) = lanes 8k..8k+7; 3-step subgroup reduce, then ballot mask.
  const int jbeg = blockIdx.x * JCHUNK + wv * (JCHUNK / 4);
  const float4* jp = (const float4*)sobs + (jbeg >> 1);
  {
    const float4 v = jp[lane];
    float bxmin = fminf(v.x, v.z), bxmax = fmaxf(v.x, v.z);
    float bymin = fminf(v.y, v.w), bymax = fmaxf(v.y, v.w);
#pragma unroll
    for (int m = 1; m < 8; m <<= 1) {
      bxmin = fminf(bxmin, __shfl_xor(bxmin, m));
      bxmax = fmaxf(bxmax, __shfl_xor(bxmax, m));
      bymin = fminf(bymin, __shfl_xor(bymin, m));
      bymax = fmaxf(bymax, __shfl_xor(bymax, m));
    }
    const bool ok = !(bxmin > gxmax + MARGIN || bxmax < gxmin - MARGIN ||
                      bymin > gymax + MARGIN || bymax < gymin - MARGIN);
    const unsigned long long mask = __ballot(ok);

    for (int k = 0; k < 8; ++k) {
      if (!((mask >> (8 * k)) & 1ull)) continue;  // scalar skip: whole batch
      const float4* bp = jp + 8 * k;
#pragma unroll
      for (int t = 0; t < 8; ++t) {
        const float4 o2 = bp[t];  // wave-uniform -> broadcast load
        {
          const v2f p = {o2.x, o2.y};
          const v2f r = __builtin_elementwise_fma(p, two, cxy);
          const int ux = (int)__builtin_floorf(__builtin_amdgcn_fmed3f(r.x, -1.0f, 6.0f));
          const int uy = (int)__builtin_floorf(__builtin_amdgcn_fmed3f(r.y, -1.0f, 6.0f));
          atomicAdd(&base[(ux * 8 + uy) * 64], 1u);
        }
        {
          const v2f p = {o2.z, o2.w};
          const v2f r = __builtin_elementwise_fma(p, two, cxy);
          const int ux = (int)__builtin_floorf(__builtin_amdgcn_fmed3f(r.x, -1.0f, 6.0f));
          const int uy = (int)__builtin_floorf(__builtin_amdgcn_fmed3f(r.y, -1.0f, 6.0f));
          atomicAdd(&base[(ux * 8 + uy) * 64], 1u);
        }
      }
    }
  }
  __syncthreads();

  // harvest interior 6x6 rows -> 18 packed u16 words, layout [chunk][w][agent]
  unsigned* gbase = partial + (size_t)blockIdx.x * PWORDS * NAGENT +
                    (size_t)blockIdx.y * 64;
  for (int k = tid; k < PWORDS * 64; k += 256) {
    const int w = k >> 6, l = k & 63;
    const int c0 = 2 * w, c1 = 2 * w + 1;
    const int r0 = (c0 / 6 + 1) * 8 + (c0 % 6 + 1);
    const int r1 = (c1 / 6 + 1) * 8 + (c1 % 6 + 1);
    gbase[(size_t)w * NAGENT + l] = cnt[r0 * 64 + l] | (cnt[r1 * 64 + l] << 16);
  }
}

// ---------------------------------------------------------------------------
// k2: reduce NCHUNK packed partials (sorted-index rows), subtract self-pair,
// GEMM occ @ W^T + b, write to the ORIGINAL agent row via sidx permutation.
// ---------------------------------------------------------------------------
__global__ __launch_bounds__(256) void occ_gemm_kernel(
    const unsigned* __restrict__ partial, const unsigned* __restrict__ sidx,
    const float* __restrict__ W, const float* __restrict__ bias,
    float* __restrict__ out) {
  __shared__ float Wl[HIDDEN * NCELL];
  __shared__ float occ[16 * CSTRIDE];
  const int tid = threadIdx.x;

  const float4* W4 = (const float4*)W;
  float4* Wl4 = (float4*)Wl;
  for (int k = tid; k < HIDDEN * NCELL / 4; k += 256) Wl4[k] = W4[k];

  const int agBase = blockIdx.x * 16;
  for (int k = tid; k < 16 * PWORDS; k += 256) {
    const int a = k & 15, w = k >> 4;
    const unsigned* p = partial + (size_t)w * NAGENT + agBase + a;
    unsigned s = 0;
#pragma unroll
    for (int c = 0; c < NCHUNK; ++c) s += p[(size_t)c * PWORDS * NAGENT];
    float lo = (float)(s & 0xFFFFu);
    float hi = (float)(s >> 16);
    if (w == 10) hi -= 1.0f;  // cell 21: remove the always-counted self-pair
    occ[a * CSTRIDE + 2 * w]     = lo;
    occ[a * CSTRIDE + 2 * w + 1] = hi;
  }
  __syncthreads();

  const int a  = tid >> 4;
  const int hg = tid & 15;

  float occf[NCELL];
#pragma unroll
  for (int c = 0; c < NCELL; ++c) occf[c] = occ[a * CSTRIDE + c];

  float acc[8];
#pragma unroll
  for (int k = 0; k < 8; ++k) acc[k] = bias[hg + 16 * k];

#pragma unroll
  for (int c4 = 0; c4 < 9; ++c4) {
#pragma unroll
    for (int k = 0; k < 8; ++k) {
      const float4 w4 = *(const float4*)&Wl[(hg + 16 * k) * NCELL + c4 * 4];
      acc[k] = fmaf(occf[4 * c4 + 0], w4.x, acc[k]);
      acc[k] = fmaf(occf[4 * c4 + 1], w4.y, acc[k]);
      acc[k] = fmaf(occf[4 * c4 + 2], w4.z, acc[k]);
      acc[k] = fmaf(occf[4 * c4 + 3], w4.w, acc[k]);
    }
  }

  float* ob = out + (size_t)sidx[agBase + a] * HIDDEN;
#pragma unroll
  for (int k = 0; k < 8; ++k) ob[hg + 16 * k] = acc[k];
}

extern "C" void kernel_launch(void* const* d_in, const int* in_sizes, int n_in,
                              void* d_out, int out_size, void* d_ws, size_t ws_size,
                              hipStream_t stream) {
  (void)in_sizes; (void)n_in; (void)out_size; (void)ws_size;
  const float2* obs = (const float2*)d_in[0];
  const float*  W   = (const float*)d_in[1];
  const float*  b   = (const float*)d_in[2];
  float* out = (float*)d_out;
  unsigned* ws = (unsigned*)d_ws;
  unsigned* partial = ws + WS_PARTIAL;
  unsigned* bcnt = ws + WS_BCNT;
  unsigned* bcur = ws + WS_BCUR;
  unsigned* sidx = ws + WS_SIDX;
  float2*   sobs = (float2*)(ws + WS_SOBS);

  hipMemsetAsync(bcnt, 0, 256 * sizeof(unsigned), stream);
  sort_count  <<<dim3(32), dim3(256), 0, stream>>>(obs, bcnt);
  sort_scan   <<<dim3(1),  dim3(256), 0, stream>>>(bcnt, bcur);
  sort_scatter<<<dim3(32), dim3(256), 0, stream>>>(obs, bcur, sidx, sobs);
  occ_hist_kernel<<<dim3(NCHUNK, 128), dim3(256), 0, stream>>>(sobs, partial);
  occ_gemm_kernel<<<dim3(512), dim3(256), 0, stream>>>(partial, sidx, W, b, out);
}